// Round 3
// baseline (294.341 us; speedup 1.0000x reference)
//
#include <hip/hip_runtime.h>

// MultiHeadSelfAttention: B=4, S=2048, D=1024, H=16, HD=64, causal. fp32 I/O, bf16 MFMA.
// R11 = R10 + KEY-SPLIT of long q-tiles. Model (validated on R8/R10): attn makespan =
// longest block's serial units x tau, tau ~= 2.55 us/kt (barrier-gated latency chain);
// R10's 83 us = 32 units x 2.6. Fixed-M softmax is associative over keys => split each
// qt>=8 into two key-chunks of qt+1 tiles (longest block 32 -> 16 units). 1536 blocks,
// long-first dispatch for backfill. Chunks write unnormalized O^T partials (f32, into
// d_out which is dead until the final GEMM) + l partials (ws); attn_combine sums,
// normalizes, writes bf16. No atomics, no inter-block ordering assumptions. Chunk 0
// never contains the diagonal (64(qt+1) <= 128qt for qt>=1) -> mask path unchanged.

typedef short s16;
typedef __attribute__((ext_vector_type(4))) short s16x4;
typedef __attribute__((ext_vector_type(8))) short bf16x8;
typedef __attribute__((ext_vector_type(4))) float f32x4;

__device__ __forceinline__ s16 f2bf(float f) {
    union { float f; unsigned int i; } v;
    v.f = f;
    unsigned int r = v.i + 0x7fffu + ((v.i >> 16) & 1u);  // RNE
    return (s16)(r >> 16);
}

// pack two fp32 -> bf16x2 dword (round-half-up)
__device__ __forceinline__ unsigned pack_bf16(float a, float b) {
    union { float f; unsigned u; } x, y;
    x.f = a; y.f = b;
    return __byte_perm(x.u + 0x8000u, y.u + 0x8000u, 0x7632);
}

__device__ __forceinline__ void load_lds16(const s16* g, s16* lds_base) {
    __builtin_amdgcn_global_load_lds(
        (const __attribute__((address_space(1))) void*)g,
        (__attribute__((address_space(3))) void*)lds_base, 16, 0, 0);
}

// ---------------------------------------------------------------------------
// fp32 -> bf16 elementwise cast
// ---------------------------------------------------------------------------
__global__ void cast_f32_bf16(const float* __restrict__ in, s16* __restrict__ out) {
    const int i = (blockIdx.x * 256 + threadIdx.x) * 4;
    const float4 f = *(const float4*)(in + i);
    s16x4 r = {f2bf(f.x), f2bf(f.y), f2bf(f.z), f2bf(f.w)};
    *(s16x4*)(out + i) = r;
}

// ---------------------------------------------------------------------------
// Transpose + cast: fp32 [R,C] -> bf16 [C,R]
// ---------------------------------------------------------------------------
__global__ void transpose_cast(const float* __restrict__ in,
                               s16* __restrict__ out, int R, int C) {
    __shared__ float tile[32][33];
    const int cb = blockIdx.x * 32, rb = blockIdx.y * 32;
    const int tx = threadIdx.x, ty = threadIdx.y;  // 32 x 8
#pragma unroll
    for (int i = 0; i < 32; i += 8)
        tile[ty + i][tx] = in[(size_t)(rb + ty + i) * C + cb + tx];
    __syncthreads();
#pragma unroll
    for (int i = 0; i < 32; i += 8)
        out[(size_t)(cb + ty + i) * R + rb + tx] = f2bf(tile[tx][ty + i]);
}

// ---------------------------------------------------------------------------
// C[M,N] = A[M,K] @ Bt[N,K]^T + bias[N]. A,Bt bf16; C fp32 or bf16.
// m97 structure: 128x128 tile, BK=32, global_load_lds width-16 staging. (R5-proven)
// ---------------------------------------------------------------------------
template <bool OUT_F32>
__global__ __launch_bounds__(256) void gemm_bt_bias(
    const s16* __restrict__ A,
    const s16* __restrict__ Bt,
    const float* __restrict__ bias,
    void* __restrict__ Cv,
    int M, int N, int K) {
    __shared__ __attribute__((aligned(16))) s16 As[128 * 32];
    __shared__ __attribute__((aligned(16))) s16 Bs[128 * 32];

    const int tid  = threadIdx.x;
    const int lane = tid & 63;
    const int wave = tid >> 6;
    const int l15  = lane & 15;
    const int quad = lane >> 4;
    const int m0 = blockIdx.y * 128;
    const int n0 = blockIdx.x * 128;
    const int wm = (wave & 1) * 64;
    const int wn = (wave >> 1) * 64;

    f32x4 acc[4][4];
#pragma unroll
    for (int i = 0; i < 4; ++i)
#pragma unroll
        for (int j = 0; j < 4; ++j)
            acc[i][j] = (f32x4){0.f, 0.f, 0.f, 0.f};

    const int r_a = tid >> 2;  // 0..63: row within 64-row chunk; 4 lanes/row
    const int kp  = tid & 3;

    for (int k0 = 0; k0 < K; k0 += 32) {
        __syncthreads();  // prev iteration's LDS reads done
#pragma unroll
        for (int c = 0; c < 2; ++c) {
            load_lds16(A  + (size_t)(m0 + c * 64 + r_a) * K + k0 + kp * 8, As + c * 2048 + wave * 512);
            load_lds16(Bt + (size_t)(n0 + c * 64 + r_a) * K + k0 + kp * 8, Bs + c * 2048 + wave * 512);
        }
        __syncthreads();  // vmcnt(0) drain -> staged data visible

        bf16x8 af[4], bfv[4];
#pragma unroll
        for (int mt = 0; mt < 4; ++mt)
            af[mt] = *(const bf16x8*)(As + (wm + mt * 16 + l15) * 32 + quad * 8);
#pragma unroll
        for (int nt = 0; nt < 4; ++nt)
            bfv[nt] = *(const bf16x8*)(Bs + (wn + nt * 16 + l15) * 32 + quad * 8);
#pragma unroll
        for (int mt = 0; mt < 4; ++mt)
#pragma unroll
            for (int nt = 0; nt < 4; ++nt)
                acc[mt][nt] = __builtin_amdgcn_mfma_f32_16x16x32_bf16(af[mt], bfv[nt], acc[mt][nt], 0, 0, 0);
    }

#pragma unroll
    for (int nt = 0; nt < 4; ++nt) {
        const int col = n0 + wn + nt * 16 + l15;
        const float bv = bias[col];
#pragma unroll
        for (int mt = 0; mt < 4; ++mt) {
            const int rowb = m0 + wm + mt * 16 + quad * 4;
#pragma unroll
            for (int r = 0; r < 4; ++r) {
                const float v = acc[mt][nt][r] + bv;
                if constexpr (OUT_F32)
                    ((float*)Cv)[(size_t)(rowb + r) * N + col] = v;
                else
                    ((s16*)Cv)[(size_t)(rowb + r) * N + col] = f2bf(v);
            }
        }
    }
}

// ---------------------------------------------------------------------------
// Flash attention (causal), fixed-M softmax, S^T formulation, KEY-SPLIT grid.
// 1536 blocks: bid<1024: split chunks, qt = 15-(bid>>7), bh=(bid>>1)&63, c=bid&1,
//   chunk covers kt in [c*(qt+1), (c+1)*(qt+1)) of nkt=2qt+2 tiles (qt+1 units).
// bid>=1024: unsplit, qt = 7-((bid-1024)>>6), bh=(bid-1024)&63, full range.
// Long blocks first (LPT) -> backfill. Split blocks write unnormalized O^T f32
// partials + l partials to slot (bh*8+qt-8)*2+c; attn_combine normalizes.
// ---------------------------------------------------------------------------
__global__ __launch_bounds__(256) void attn_fwd(
    const s16* __restrict__ qkv,
    s16* __restrict__ attn,
    float* __restrict__ part,
    float* __restrict__ lpart) {
    __shared__ __attribute__((aligned(16))) s16 Ks[64 * 72];
    __shared__ __attribute__((aligned(16))) s16 Vt[64 * 72];
    __shared__ __attribute__((aligned(16))) s16 PT[4][32][88];

    const int tid  = threadIdx.x;
    const int lane = tid & 63;
    const int wave = tid >> 6;
    const int l15  = lane & 15;
    const int quad = lane >> 4;

    // block decode (see header comment)
    const int bid = blockIdx.x;
    int qt, bh, c0;
    bool split;
    if (bid < 1024) {
        split = true;
        qt = 15 - (bid >> 7);
        bh = (bid >> 1) & 63;
        c0 = bid & 1;
    } else {
        split = false;
        const int u = bid - 1024;
        qt = 7 - (u >> 6);
        bh = u & 63;
        c0 = 0;
    }
    const int h = qt + 1;
    const int kt_begin = split ? c0 * h : 0;
    const int kt_end   = split ? (c0 + 1) * h : 2 * qt + 2;

    const size_t rowbase = (size_t)(bh >> 4) * 2048;
    const int hoff = (bh & 15) * 64;
    const int kp  = tid >> 3;  // 0..31: staged key-pair {2kp, 2kp+1}
    const int p_s = tid & 7;   // hd granule
    const int kg  = kp >> 2;   // key granule of this thread's pair

    const float C2 = 0.18033688011112042f;  // 0.125 * log2(e)
    const float M2 = 12.0f;                 // fixed shift (softmax shift-invariant)

    const int wq = qt * 128 + wave * 32;

    // Q fragments: lane holds Q[q = wq + qs*16 + l15][d = ks*32 + quad*8 + j]
    bf16x8 qf[2][2];
#pragma unroll
    for (int qs = 0; qs < 2; ++qs)
#pragma unroll
        for (int ks = 0; ks < 2; ++ks)
            qf[qs][ks] = *(const bf16x8*)(qkv + (rowbase + wq + qs * 16 + l15) * 3072 + hoff + ks * 32 + quad * 8);

    float l_lane[2] = {0.f, 0.f};
    f32x4 o[2][4];  // [qs][hs]; C-layout: q-col = l15, hd-row = hs*16 + quad*4 + r
#pragma unroll
    for (int qs = 0; qs < 2; ++qs)
#pragma unroll
        for (int hs = 0; hs < 4; ++hs)
            o[qs][hs] = (f32x4){0.f, 0.f, 0.f, 0.f};

    // prefetch first tile of this chunk
    bf16x8 kv[2], vv[2];
#pragma unroll
    for (int dk = 0; dk < 2; ++dk) {
        const s16* g = qkv + (rowbase + kt_begin * 64 + 2 * kp + dk) * 3072 + hoff + p_s * 8;
        kv[dk] = *(const bf16x8*)(g + 1024);
        vv[dk] = *(const bf16x8*)(g + 2048);
    }

    for (int kt = kt_begin; kt < kt_end; ++kt) {
        const int k0 = kt * 64;
        __syncthreads();  // prev iteration's LDS reads done
#pragma unroll
        for (int dk = 0; dk < 2; ++dk)  // K natural layout (R5-proven)
            *(bf16x8*)(Ks + (2 * kp + dk) * 72 + p_s * 8) = kv[dk];
#pragma unroll
        for (int j = 0; j < 8; ++j) {   // V^T swizzled, key-pair b32 (R7-verified)
            const unsigned dw = (unsigned)(unsigned short)vv[0][j] |
                                ((unsigned)(unsigned short)vv[1][j] << 16);
            *(unsigned*)(Vt + (p_s * 8 + j) * 72 + ((kg ^ p_s) << 3) + (2 * kp & 7)) = dw;
        }
        __syncthreads();

        if (kt + 1 < kt_end) {  // prefetch next tile under compute
#pragma unroll
            for (int dk = 0; dk < 2; ++dk) {
                const s16* g = qkv + (rowbase + k0 + 64 + 2 * kp + dk) * 3072 + hoff + p_s * 8;
                kv[dk] = *(const bf16x8*)(g + 1024);
                vv[dk] = *(const bf16x8*)(g + 2048);
            }
        }

        if (k0 > wq + 31) continue;  // fully masked for this wave

        // S^T = K Q^T : st[qs][kb], key subtiles kb of 16
        f32x4 st[2][4];
#pragma unroll
        for (int qs = 0; qs < 2; ++qs)
#pragma unroll
            for (int kb = 0; kb < 4; ++kb)
                st[qs][kb] = (f32x4){0.f, 0.f, 0.f, 0.f};
        __builtin_amdgcn_s_setprio(1);
#pragma unroll
        for (int kb = 0; kb < 4; ++kb)
#pragma unroll
            for (int ks = 0; ks < 2; ++ks) {
                const bf16x8 kf = *(const bf16x8*)(Ks + (kb * 16 + l15) * 72 + ks * 32 + quad * 8);
#pragma unroll
                for (int qs = 0; qs < 2; ++qs)
                    st[qs][kb] = __builtin_amdgcn_mfma_f32_16x16x32_bf16(kf, qf[qs][ks], st[qs][kb], 0, 0, 0);
            }
        __builtin_amdgcn_s_setprio(0);

        // softmax (fixed-M) + P^T -> PT (b64, conflict-free)
        const bool edge = (k0 + 63 > wq);
#pragma unroll
        for (int qs = 0; qs < 2; ++qs) {
            const int q = wq + qs * 16 + l15;
#pragma unroll
            for (int kb = 0; kb < 4; ++kb) {
                float p4[4];
#pragma unroll
                for (int r = 0; r < 4; ++r) {
                    float t = fmaf(st[qs][kb][r], C2, -M2);
                    if (edge) {
                        const int key = k0 + kb * 16 + quad * 4 + r;
                        t = (key <= q) ? t : -150.f;  // exp2(-150) == 0
                    }
                    p4[r] = __builtin_amdgcn_exp2f(t);
                    l_lane[qs] += p4[r];
                }
                uint2 dd;
                dd.x = pack_bf16(p4[0], p4[1]);
                dd.y = pack_bf16(p4[2], p4[3]);
                *(uint2*)(&PT[wave][qs * 16 + l15][kb * 16 + quad * 4]) = dd;
            }
        }

        // O^T += V^T P^T
        __builtin_amdgcn_s_setprio(1);
#pragma unroll
        for (int kk = 0; kk < 2; ++kk) {
            bf16x8 pf[2];
#pragma unroll
            for (int qs = 0; qs < 2; ++qs)
                pf[qs] = *(const bf16x8*)(&PT[wave][qs * 16 + l15][kk * 32 + quad * 8]);
#pragma unroll
            for (int hs = 0; hs < 4; ++hs) {
                const bf16x8 vf = *(const bf16x8*)(
                    Vt + (hs * 16 + l15) * 72 + (((kk * 4 + quad) ^ (2 * hs + (l15 >> 3))) << 3));
#pragma unroll
                for (int qs = 0; qs < 2; ++qs)
                    o[qs][hs] = __builtin_amdgcn_mfma_f32_16x16x32_bf16(vf, pf[qs], o[qs][hs], 0, 0, 0);
            }
        }
        __builtin_amdgcn_s_setprio(0);
    }

    // l: sum across the 4 quads (lanes with same l15)
    float lsum[2];
#pragma unroll
    for (int qs = 0; qs < 2; ++qs) {
        float l = l_lane[qs];
        l += __shfl_xor(l, 16);
        l += __shfl_xor(l, 32);
        lsum[qs] = l;
    }

    if (!split) {
        // epilogue: O^T[hd][q] -> attn[q][hoff+hd]; 4 consecutive hd per reg-quad -> b64
#pragma unroll
        for (int qs = 0; qs < 2; ++qs) {
            const float rl = 1.f / lsum[qs];
            const int q = wq + qs * 16 + l15;
#pragma unroll
            for (int hs = 0; hs < 4; ++hs) {
                uint2 dd;
                dd.x = pack_bf16(o[qs][hs][0] * rl, o[qs][hs][1] * rl);
                dd.y = pack_bf16(o[qs][hs][2] * rl, o[qs][hs][3] * rl);
                *(uint2*)(attn + (rowbase + q) * 1024 + hoff + hs * 16 + quad * 4) = dd;
            }
        }
    } else {
        // store unnormalized O^T partial (f32) + l partial
        const int slot = (bh * 8 + (qt - 8)) * 2 + c0;
        float* pslot = part + (size_t)slot * 8192;
#pragma unroll
        for (int qs = 0; qs < 2; ++qs) {
            const int qrel = wave * 32 + qs * 16 + l15;
#pragma unroll
            for (int hs = 0; hs < 4; ++hs)
                *(f32x4*)(pslot + qrel * 64 + hs * 16 + quad * 4) = o[qs][hs];
            if (quad == 0)
                lpart[(size_t)slot * 128 + qrel] = lsum[qs];
        }
    }
}

// ---------------------------------------------------------------------------
// Combine split partials: attn[q][hd] = (P0 + P1) / (l0 + l1), bf16.
// grid 512 = (bh 64) x (qt-8 in 0..7); 256 threads; thread = (q = t>>1, hd half).
// ---------------------------------------------------------------------------
__global__ __launch_bounds__(256) void attn_combine(
    const float* __restrict__ part,
    const float* __restrict__ lpart,
    s16* __restrict__ attn) {
    const int b  = blockIdx.x;        // bh*8 + (qt-8)
    const int bh = b >> 3;
    const int qt = (b & 7) + 8;
    const size_t rowbase = (size_t)(bh >> 4) * 2048;
    const int hoff = (bh & 15) * 64;
    const int t = threadIdx.x;
    const int q = t >> 1;             // 0..127 within tile
    const int hd0 = (t & 1) * 32;
    const float l = lpart[(size_t)(2 * b) * 128 + q] + lpart[(size_t)(2 * b + 1) * 128 + q];
    const float rl = 1.f / l;
    const float* p0 = part + (size_t)(2 * b) * 8192 + q * 64 + hd0;
    const float* p1 = part + (size_t)(2 * b + 1) * 8192 + q * 64 + hd0;
    s16* dst = attn + (rowbase + qt * 128 + q) * 1024 + hoff + hd0;
#pragma unroll
    for (int j = 0; j < 8; ++j) {     // 8 x float4 = 32 fp32 -> 32 bf16
        const float4 a = ((const float4*)p0)[j];
        const float4 c = ((const float4*)p1)[j];
        uint2 dd;
        dd.x = pack_bf16((a.x + c.x) * rl, (a.y + c.y) * rl);
        dd.y = pack_bf16((a.z + c.z) * rl, (a.w + c.w) * rl);
        ((uint2*)dst)[j] = dd;
    }
}

// ---------------------------------------------------------------------------
extern "C" void kernel_launch(void* const* d_in, const int* in_sizes, int n_in,
                              void* d_out, int out_size, void* d_ws, size_t ws_size,
                              hipStream_t stream) {
    const float* x    = (const float*)d_in[0];  // [8192,1024]
    const float* Wqkv = (const float*)d_in[1];  // [1024,3072]
    const float* bqkv = (const float*)d_in[2];  // [3072]
    const float* Wout = (const float*)d_in[3];  // [1024,1024]
    const float* bout = (const float*)d_in[4];  // [1024]
    float* out = (float*)d_out;                 // [8192,1024] fp32

    s16* ws   = (s16*)d_ws;
    s16* qkv  = ws;                          // [8192,3072] bf16
    s16* xba  = qkv + (size_t)8192 * 3072;   // [8192,1024] bf16: x-cast, later attn output
    s16* wtq  = xba + (size_t)8192 * 1024;   // [3072,1024] bf16
    s16* wto  = wtq + (size_t)3072 * 1024;   // [1024,1024] bf16
    float* lpart = (float*)(wto + (size_t)1024 * 1024);  // [1024][128] f32

    // O^T partials live in d_out (dead until final GEMM): 1024 slots x 8192 f32 = 32 MB
    float* part = out;

    cast_f32_bf16<<<8192, 256, 0, stream>>>(x, xba);
    transpose_cast<<<dim3(3072 / 32, 1024 / 32), dim3(32, 8), 0, stream>>>(Wqkv, wtq, 1024, 3072);
    transpose_cast<<<dim3(1024 / 32, 1024 / 32), dim3(32, 8), 0, stream>>>(Wout, wto, 1024, 1024);
    gemm_bt_bias<false><<<dim3(3072 / 128, 8192 / 128), 256, 0, stream>>>(
        xba, wtq, bqkv, qkv, 8192, 3072, 1024);
    attn_fwd<<<1536, 256, 0, stream>>>(qkv, xba, part, lpart);  // xba dead; reused as attn buf
    attn_combine<<<512, 256, 0, stream>>>(part, lpart, xba);
    gemm_bt_bias<true><<<dim3(1024 / 128, 8192 / 128), 256, 0, stream>>>(
        xba, wto, bout, out, 8192, 1024, 1024);
}

// Round 5
// 268.977 us; speedup vs baseline: 1.0943x; 1.0943x over previous
//
#include <hip/hip_runtime.h>

// MultiHeadSelfAttention: B=4, S=2048, D=1024, H=16, HD=64, causal. fp32 I/O, bf16 MFMA.
// R13 = R12 resubmit with hardened sync (R12 bench died: "container failed twice", no
// counters; audit found no kernel bug -> likely infra, but hedging). Changes vs R12:
// prologue and tile-boundary drains use __syncthreads() (canonical vmcnt(0)+lgkmcnt(0)
// +s_barrier) instead of hand-rolled asm; intra-tile phase barriers stay raw.
// Design (from R12): R10 attn (83 us, balanced 1024-block grid) + 8-phase GEMM:
//   BM=128 BN=256 BK=64, 512 thr (8 waves 2Mx4N), LDS 96KB dbuf, grids exact
//   machine multiples (QKV 768 = 3 rounds, OUT 256 = 1 round).
//   Per K-tile 4 sub-phases {8 ds_read_b128 -> stage-issue(p0,p1) -> barrier ->
//   setprio+8 MFMA -> barrier}; ONE drain per tile at p3 (loads ~2-3 phases old,
//   never a mid-loop vmcnt-0 stall while compute pending).
//   LDS XOR swizzle g' = g^(row&7) applied BOTH sides (pre-swizzled global source for
//   linear global_load_lds dest + swizzled ds_read) — bank-verified conflict-free.

typedef short s16;
typedef __attribute__((ext_vector_type(4))) short s16x4;
typedef __attribute__((ext_vector_type(8))) short bf16x8;
typedef __attribute__((ext_vector_type(4))) float f32x4;

__device__ __forceinline__ s16 f2bf(float f) {
    union { float f; unsigned int i; } v;
    v.f = f;
    unsigned int r = v.i + 0x7fffu + ((v.i >> 16) & 1u);  // RNE
    return (s16)(r >> 16);
}

// pack two fp32 -> bf16x2 dword (round-half-up)
__device__ __forceinline__ unsigned pack_bf16(float a, float b) {
    union { float f; unsigned u; } x, y;
    x.f = a; y.f = b;
    return __byte_perm(x.u + 0x8000u, y.u + 0x8000u, 0x7632);
}

__device__ __forceinline__ void load_lds16(const s16* g, s16* lds_base) {
    __builtin_amdgcn_global_load_lds(
        (const __attribute__((address_space(1))) void*)g,
        (__attribute__((address_space(3))) void*)lds_base, 16, 0, 0);
}

// ---------------------------------------------------------------------------
// fp32 -> bf16 elementwise cast
// ---------------------------------------------------------------------------
__global__ void cast_f32_bf16(const float* __restrict__ in, s16* __restrict__ out) {
    const int i = (blockIdx.x * 256 + threadIdx.x) * 4;
    const float4 f = *(const float4*)(in + i);
    s16x4 r = {f2bf(f.x), f2bf(f.y), f2bf(f.z), f2bf(f.w)};
    *(s16x4*)(out + i) = r;
}

// ---------------------------------------------------------------------------
// Transpose + cast: fp32 [R,C] -> bf16 [C,R]
// ---------------------------------------------------------------------------
__global__ void transpose_cast(const float* __restrict__ in,
                               s16* __restrict__ out, int R, int C) {
    __shared__ float tile[32][33];
    const int cb = blockIdx.x * 32, rb = blockIdx.y * 32;
    const int tx = threadIdx.x, ty = threadIdx.y;  // 32 x 8
#pragma unroll
    for (int i = 0; i < 32; i += 8)
        tile[ty + i][tx] = in[(size_t)(rb + ty + i) * C + cb + tx];
    __syncthreads();
#pragma unroll
    for (int i = 0; i < 32; i += 8)
        out[(size_t)(cb + ty + i) * R + rb + tx] = f2bf(tile[tx][ty + i]);
}

// ---------------------------------------------------------------------------
// C[M,N] = A[M,K] @ Bt[N,K]^T + bias[N]. A,Bt bf16; C fp32 or bf16.
// 8-phase pipelined 128x256 tile (see file header). Requires M%128==0, N%256==0,
// K%64==0.
// ---------------------------------------------------------------------------
template <bool OUT_F32>
__global__ __launch_bounds__(512, 2) void gemm_bt_bias_8p(
    const s16* __restrict__ A,
    const s16* __restrict__ Bt,
    const float* __restrict__ bias,
    void* __restrict__ Cv,
    int M, int N, int K) {
    __shared__ __attribute__((aligned(16))) s16 As[2][128 * 64];
    __shared__ __attribute__((aligned(16))) s16 Bs[2][256 * 64];

    const int tid  = threadIdx.x;
    const int lane = tid & 63;
    const int wave = tid >> 6;   // 0..7
    const int l15  = lane & 15;
    const int quad = lane >> 4;
    const int wr   = wave >> 2;  // 0..1 (M)
    const int wc   = wave & 3;   // 0..3 (N)
    const int m0 = blockIdx.y * 128;
    const int n0 = blockIdx.x * 256;

    // staging: thread t covers row srow of a 64-row unit, LDS granule tid&7;
    // source granule pre-swizzled (g ^ (row&7)) so swizzled READS see logical data
    // (both-sides-or-neither with linear global_load_lds dest).
    const int srow = tid >> 3;                 // 0..63
    const int sg   = (tid & 7) ^ (srow & 7);   // pre-swizzled global granule
    const s16* Ag = A  + (size_t)(m0 + srow) * K + sg * 8;
    const s16* Bg = Bt + (size_t)(n0 + srow) * K + sg * 8;

#define STAGE_A8(buf, h, kt) load_lds16(Ag + (size_t)(h) * 64 * K + (size_t)(kt) * 64, \
                                        &As[buf][(h) * 4096 + wave * 512])
#define STAGE_B8(buf, u, kt) load_lds16(Bg + (size_t)(u) * 64 * K + (size_t)(kt) * 64, \
                                        &Bs[buf][(u) * 4096 + wave * 512])

    f32x4 acc[4][4];
#pragma unroll
    for (int i = 0; i < 4; ++i)
#pragma unroll
        for (int j = 0; j < 4; ++j)
            acc[i][j] = (f32x4){0.f, 0.f, 0.f, 0.f};

    const int nk = K >> 6;  // 64-wide K-tiles

    // prologue: stage tile 0 into buf 0, full drain + sync
    STAGE_A8(0, 0, 0); STAGE_A8(0, 1, 0);
    STAGE_B8(0, 0, 0); STAGE_B8(0, 1, 0); STAGE_B8(0, 2, 0); STAGE_B8(0, 3, 0);
    __syncthreads();

    for (int t = 0; t < nk; ++t) {
        const int buf  = t & 1;
        const int nbuf = buf ^ 1;
        const bool pre = (t + 1 < nk);
#pragma unroll
        for (int p = 0; p < 4; ++p) {
            const int mh = p >> 1, nh = p & 1;
            // ds-read this quadrant's fragments (swizzled granule)
            bf16x8 af[2][2], bfr[2][2];
#pragma unroll
            for (int i = 0; i < 2; ++i)
#pragma unroll
                for (int ks = 0; ks < 2; ++ks) {
                    const int ar = wr * 64 + (mh * 2 + i) * 16 + l15;
                    const int br = wc * 64 + (nh * 2 + i) * 16 + l15;
                    const int gs = ((ks * 4 + quad) ^ (l15 & 7)) * 8;
                    af[i][ks]  = *(const bf16x8*)(&As[buf][ar * 64 + gs]);
                    bfr[i][ks] = *(const bf16x8*)(&Bs[buf][br * 64 + gs]);
                }
            // issue next tile's staging early (phases 0-1) so it is ~2-3 phases old
            // at the tile-boundary drain (loads stay in flight across barriers)
            if (p == 0 && pre) {
                STAGE_A8(nbuf, 0, t + 1); STAGE_A8(nbuf, 1, t + 1);
                STAGE_B8(nbuf, 0, t + 1);
            }
            if (p == 1 && pre) {
                STAGE_B8(nbuf, 1, t + 1); STAGE_B8(nbuf, 2, t + 1);
                STAGE_B8(nbuf, 3, t + 1);
            }
            __builtin_amdgcn_s_barrier();  // phase-align waves (no memory semantics)
            __builtin_amdgcn_s_setprio(1);
#pragma unroll
            for (int i = 0; i < 2; ++i)
#pragma unroll
                for (int j = 0; j < 2; ++j)
#pragma unroll
                    for (int ks = 0; ks < 2; ++ks)
                        acc[mh * 2 + i][nh * 2 + j] = __builtin_amdgcn_mfma_f32_16x16x32_bf16(
                            af[i][ks], bfr[j][ks], acc[mh * 2 + i][nh * 2 + j], 0, 0, 0);
            __builtin_amdgcn_s_setprio(0);
            if (p == 3)
                __syncthreads();  // tile boundary: drain staging + sync (vmcnt0+lgkm0+bar)
            else
                __builtin_amdgcn_s_barrier();
        }
    }
#undef STAGE_A8
#undef STAGE_B8

    // epilogue
#pragma unroll
    for (int nt = 0; nt < 4; ++nt) {
        const int col = n0 + wc * 64 + nt * 16 + l15;
        const float bv = bias[col];
#pragma unroll
        for (int mt = 0; mt < 4; ++mt) {
            const int rowb = m0 + wr * 64 + mt * 16 + quad * 4;
#pragma unroll
            for (int r = 0; r < 4; ++r) {
                const float v = acc[mt][nt][r] + bv;
                if constexpr (OUT_F32)
                    ((float*)Cv)[(size_t)(rowb + r) * N + col] = v;
                else
                    ((s16*)Cv)[(size_t)(rowb + r) * N + col] = f2bf(v);
            }
        }
    }
}

// ---------------------------------------------------------------------------
// Flash attention (causal), fixed-M softmax, S^T formulation. (R10, 83 us proven)
// Flat grid of 1024 blocks = 4/CU resident. bid bits: hi=bid>>8 (CU-sharing round),
// bh=(bid>>2)&63, a=bid&3; qt = hi&1 ? 15-(2a+(hi>>1)) : 2a+(hi>>1).
// -> per-CU qt sets {x, 15-x, x+1, 14-x}: exactly 68 key-tile units per CU.
// St = K Q^T per 16x16 subtile. C-layout: q = l15, key = quad*4+r.
// PT per-wave [32 q][88]: b64 stores / b128 reads, bank-verified conflict-free.
// O^T = V^T P^T: A = V^T-frag (swizzled Vt), B = P^T from PT.
// ---------------------------------------------------------------------------
__global__ __launch_bounds__(256) void attn_fwd(
    const s16* __restrict__ qkv,
    s16* __restrict__ attn) {
    __shared__ __attribute__((aligned(16))) s16 Ks[64 * 72];
    __shared__ __attribute__((aligned(16))) s16 Vt[64 * 72];
    __shared__ __attribute__((aligned(16))) s16 PT[4][32][88];

    const int tid  = threadIdx.x;
    const int lane = tid & 63;
    const int wave = tid >> 6;
    const int l15  = lane & 15;
    const int quad = lane >> 4;

    // balanced (bh, qt) decomposition (see header comment)
    const int bid = blockIdx.x;
    const int hi  = bid >> 8;
    const int a   = bid & 3;
    const int bh  = (bid >> 2) & 63;
    const int qbase = a * 2 + (hi >> 1);
    const int qt  = (hi & 1) ? 15 - qbase : qbase;

    const size_t rowbase = (size_t)(bh >> 4) * 2048;
    const int hoff = (bh & 15) * 64;
    const int kp  = tid >> 3;  // 0..31: staged key-pair {2kp, 2kp+1}
    const int p_s = tid & 7;   // hd granule
    const int kg  = kp >> 2;   // key granule of this thread's pair

    const float C2 = 0.18033688011112042f;  // 0.125 * log2(e)
    const float M2 = 12.0f;                 // fixed shift (softmax shift-invariant)

    const int wq = qt * 128 + wave * 32;

    // Q fragments: lane holds Q[q = wq + qs*16 + l15][d = ks*32 + quad*8 + j]
    bf16x8 qf[2][2];
#pragma unroll
    for (int qs = 0; qs < 2; ++qs)
#pragma unroll
        for (int ks = 0; ks < 2; ++ks)
            qf[qs][ks] = *(const bf16x8*)(qkv + (rowbase + wq + qs * 16 + l15) * 3072 + hoff + ks * 32 + quad * 8);

    float l_lane[2] = {0.f, 0.f};
    f32x4 o[2][4];  // [qs][hs]; C-layout: q-col = l15, hd-row = hs*16 + quad*4 + r
#pragma unroll
    for (int qs = 0; qs < 2; ++qs)
#pragma unroll
        for (int hs = 0; hs < 4; ++hs)
            o[qs][hs] = (f32x4){0.f, 0.f, 0.f, 0.f};

    const int nkt = qt * 2 + 2;
    // prefetch tile 0 K/V
    bf16x8 kv[2], vv[2];
#pragma unroll
    for (int dk = 0; dk < 2; ++dk) {
        const s16* g = qkv + (rowbase + 2 * kp + dk) * 3072 + hoff + p_s * 8;
        kv[dk] = *(const bf16x8*)(g + 1024);
        vv[dk] = *(const bf16x8*)(g + 2048);
    }

    for (int kt = 0; kt < nkt; ++kt) {
        const int k0 = kt * 64;
        __syncthreads();  // prev iteration's LDS reads done
#pragma unroll
        for (int dk = 0; dk < 2; ++dk)  // K natural layout (R5-proven)
            *(bf16x8*)(Ks + (2 * kp + dk) * 72 + p_s * 8) = kv[dk];
#pragma unroll
        for (int j = 0; j < 8; ++j) {   // V^T swizzled, key-pair b32 (R7-verified)
            const unsigned dw = (unsigned)(unsigned short)vv[0][j] |
                                ((unsigned)(unsigned short)vv[1][j] << 16);
            *(unsigned*)(Vt + (p_s * 8 + j) * 72 + ((kg ^ p_s) << 3) + (2 * kp & 7)) = dw;
        }
        __syncthreads();

        if (kt + 1 < nkt) {  // prefetch next tile under compute
#pragma unroll
            for (int dk = 0; dk < 2; ++dk) {
                const s16* g = qkv + (rowbase + k0 + 64 + 2 * kp + dk) * 3072 + hoff + p_s * 8;
                kv[dk] = *(const bf16x8*)(g + 1024);
                vv[dk] = *(const bf16x8*)(g + 2048);
            }
        }

        if (k0 > wq + 31) continue;  // fully masked for this wave

        // S^T = K Q^T : st[qs][kb], key subtiles kb of 16
        f32x4 st[2][4];
#pragma unroll
        for (int qs = 0; qs < 2; ++qs)
#pragma unroll
            for (int kb = 0; kb < 4; ++kb)
                st[qs][kb] = (f32x4){0.f, 0.f, 0.f, 0.f};
        __builtin_amdgcn_s_setprio(1);
#pragma unroll
        for (int kb = 0; kb < 4; ++kb)
#pragma unroll
            for (int ks = 0; ks < 2; ++ks) {
                const bf16x8 kf = *(const bf16x8*)(Ks + (kb * 16 + l15) * 72 + ks * 32 + quad * 8);
#pragma unroll
                for (int qs = 0; qs < 2; ++qs)
                    st[qs][kb] = __builtin_amdgcn_mfma_f32_16x16x32_bf16(kf, qf[qs][ks], st[qs][kb], 0, 0, 0);
            }
        __builtin_amdgcn_s_setprio(0);

        // softmax (fixed-M) + P^T -> PT (b64, conflict-free)
        const bool edge = (k0 + 63 > wq);
#pragma unroll
        for (int qs = 0; qs < 2; ++qs) {
            const int q = wq + qs * 16 + l15;
#pragma unroll
            for (int kb = 0; kb < 4; ++kb) {
                float p4[4];
#pragma unroll
                for (int r = 0; r < 4; ++r) {
                    float t = fmaf(st[qs][kb][r], C2, -M2);
                    if (edge) {
                        const int key = k0 + kb * 16 + quad * 4 + r;
                        t = (key <= q) ? t : -150.f;  // exp2(-150) == 0
                    }
                    p4[r] = __builtin_amdgcn_exp2f(t);
                    l_lane[qs] += p4[r];
                }
                uint2 dd;
                dd.x = pack_bf16(p4[0], p4[1]);
                dd.y = pack_bf16(p4[2], p4[3]);
                *(uint2*)(&PT[wave][qs * 16 + l15][kb * 16 + quad * 4]) = dd;
            }
        }

        // O^T += V^T P^T
        __builtin_amdgcn_s_setprio(1);
#pragma unroll
        for (int kk = 0; kk < 2; ++kk) {
            bf16x8 pf[2];
#pragma unroll
            for (int qs = 0; qs < 2; ++qs)
                pf[qs] = *(const bf16x8*)(&PT[wave][qs * 16 + l15][kk * 32 + quad * 8]);
#pragma unroll
            for (int hs = 0; hs < 4; ++hs) {
                const bf16x8 vf = *(const bf16x8*)(
                    Vt + (hs * 16 + l15) * 72 + (((kk * 4 + quad) ^ (2 * hs + (l15 >> 3))) << 3));
#pragma unroll
                for (int qs = 0; qs < 2; ++qs)
                    o[qs][hs] = __builtin_amdgcn_mfma_f32_16x16x32_bf16(vf, pf[qs], o[qs][hs], 0, 0, 0);
            }
        }
        __builtin_amdgcn_s_setprio(0);
    }

    // l: sum across the 4 quads (lanes with same l15)
    float rl[2];
#pragma unroll
    for (int qs = 0; qs < 2; ++qs) {
        float l = l_lane[qs];
        l += __shfl_xor(l, 16);
        l += __shfl_xor(l, 32);
        rl[qs] = 1.f / l;
    }

    // epilogue: O^T[hd][q] -> attn[q][hoff+hd]; 4 consecutive hd per reg-quad -> b64
#pragma unroll
    for (int qs = 0; qs < 2; ++qs) {
        const int q = wq + qs * 16 + l15;
#pragma unroll
        for (int hs = 0; hs < 4; ++hs) {
            uint2 dd;
            dd.x = pack_bf16(o[qs][hs][0] * rl[qs], o[qs][hs][1] * rl[qs]);
            dd.y = pack_bf16(o[qs][hs][2] * rl[qs], o[qs][hs][3] * rl[qs]);
            *(uint2*)(attn + (rowbase + q) * 1024 + hoff + hs * 16 + quad * 4) = dd;
        }
    }
}

// ---------------------------------------------------------------------------
extern "C" void kernel_launch(void* const* d_in, const int* in_sizes, int n_in,
                              void* d_out, int out_size, void* d_ws, size_t ws_size,
                              hipStream_t stream) {
    const float* x    = (const float*)d_in[0];  // [8192,1024]
    const float* Wqkv = (const float*)d_in[1];  // [1024,3072]
    const float* bqkv = (const float*)d_in[2];  // [3072]
    const float* Wout = (const float*)d_in[3];  // [1024,1024]
    const float* bout = (const float*)d_in[4];  // [1024]
    float* out = (float*)d_out;                 // [8192,1024] fp32

    s16* ws   = (s16*)d_ws;
    s16* qkv  = ws;                          // [8192,3072] bf16
    s16* xba  = qkv + (size_t)8192 * 3072;   // [8192,1024] bf16: x-cast, later attn output
    s16* wtq  = xba + (size_t)8192 * 1024;   // [3072,1024] bf16
    s16* wto  = wtq + (size_t)3072 * 1024;   // [1024,1024] bf16

    cast_f32_bf16<<<8192, 256, 0, stream>>>(x, xba);
    transpose_cast<<<dim3(3072 / 32, 1024 / 32), dim3(32, 8), 0, stream>>>(Wqkv, wtq, 1024, 3072);
    transpose_cast<<<dim3(1024 / 32, 1024 / 32), dim3(32, 8), 0, stream>>>(Wout, wto, 1024, 1024);
    gemm_bt_bias_8p<false><<<dim3(3072 / 256, 8192 / 128), 512, 0, stream>>>(
        xba, wtq, bqkv, qkv, 8192, 3072, 1024);
    attn_fwd<<<1024, 256, 0, stream>>>(qkv, xba);  // xba dead; reused as attn buf
    gemm_bt_bias_8p<true><<<dim3(1024 / 256, 8192 / 128), 512, 0, stream>>>(
        xba, wto, bout, out, 8192, 1024, 1024);
}

// Round 6
// 268.821 us; speedup vs baseline: 1.0949x; 1.0006x over previous
//
#include <hip/hip_runtime.h>

// MultiHeadSelfAttention: B=4, S=2048, D=1024, H=16, HD=64, causal. fp32 I/O, bf16 MFMA.
// R14 = R13 attn (80 us) + m201-geometry GEMM. R13 datum: two structurally different
// GEMMs both ~390 TF -> bottleneck is the 64x64-per-wave geometry's LDS-bytes/FLOP
// (16-32KB LDS read per wave per K-tile vs MFMA floor), not the barrier schedule.
// New GEMM: BM=BN=256 BK=64, 8 waves (2Mx4N, 128x64 out/wave), 128KB LDS dbuf.
//   Per K-tile 4 phases x 16 MFMA; B-frags (8 b128) read ONCE per tile into regs,
//   A-quadrant (4 b128) per phase -> 24KB LDS/wave/tile (below MFMA time at 256B/clk).
//   All 8 staging gload_lds issued in phases 0-1 -> 2-3 phases old at the single
//   boundary drain (__syncthreads). Both-sides XOR granule swizzle (R13-proven).
//   T1 XCD-bijective swizzle (QKV 384 blocks, OUT 128; both %8==0).

typedef short s16;
typedef __attribute__((ext_vector_type(4))) short s16x4;
typedef __attribute__((ext_vector_type(8))) short bf16x8;
typedef __attribute__((ext_vector_type(4))) float f32x4;

__device__ __forceinline__ s16 f2bf(float f) {
    union { float f; unsigned int i; } v;
    v.f = f;
    unsigned int r = v.i + 0x7fffu + ((v.i >> 16) & 1u);  // RNE
    return (s16)(r >> 16);
}

// pack two fp32 -> bf16x2 dword (round-half-up)
__device__ __forceinline__ unsigned pack_bf16(float a, float b) {
    union { float f; unsigned u; } x, y;
    x.f = a; y.f = b;
    return __byte_perm(x.u + 0x8000u, y.u + 0x8000u, 0x7632);
}

__device__ __forceinline__ void load_lds16(const s16* g, s16* lds_base) {
    __builtin_amdgcn_global_load_lds(
        (const __attribute__((address_space(1))) void*)g,
        (__attribute__((address_space(3))) void*)lds_base, 16, 0, 0);
}

// ---------------------------------------------------------------------------
// fp32 -> bf16 elementwise cast
// ---------------------------------------------------------------------------
__global__ void cast_f32_bf16(const float* __restrict__ in, s16* __restrict__ out) {
    const int i = (blockIdx.x * 256 + threadIdx.x) * 4;
    const float4 f = *(const float4*)(in + i);
    s16x4 r = {f2bf(f.x), f2bf(f.y), f2bf(f.z), f2bf(f.w)};
    *(s16x4*)(out + i) = r;
}

// ---------------------------------------------------------------------------
// Transpose + cast: fp32 [R,C] -> bf16 [C,R]
// ---------------------------------------------------------------------------
__global__ void transpose_cast(const float* __restrict__ in,
                               s16* __restrict__ out, int R, int C) {
    __shared__ float tile[32][33];
    const int cb = blockIdx.x * 32, rb = blockIdx.y * 32;
    const int tx = threadIdx.x, ty = threadIdx.y;  // 32 x 8
#pragma unroll
    for (int i = 0; i < 32; i += 8)
        tile[ty + i][tx] = in[(size_t)(rb + ty + i) * C + cb + tx];
    __syncthreads();
#pragma unroll
    for (int i = 0; i < 32; i += 8)
        out[(size_t)(cb + ty + i) * R + rb + tx] = f2bf(tile[tx][ty + i]);
}

// ---------------------------------------------------------------------------
// C[M,N] = A[M,K] @ Bt[N,K]^T + bias[N]. A,Bt bf16; C fp32 or bf16.
// 256x256 tile, BK=64, 8 waves (2Mx4N, 128x64/wave). Flat grid (nwg%8==0), gx =
// N-tiles. Requires M%256==0, N%256==0, K%64==0.
// ---------------------------------------------------------------------------
template <bool OUT_F32>
__global__ __launch_bounds__(512, 2) void gemm_bt_bias_256(
    const s16* __restrict__ A,
    const s16* __restrict__ Bt,
    const float* __restrict__ bias,
    void* __restrict__ Cv,
    int M, int N, int K, int gx) {
    __shared__ __attribute__((aligned(16))) s16 As[2][256 * 64];
    __shared__ __attribute__((aligned(16))) s16 Bs[2][256 * 64];

    const int tid  = threadIdx.x;
    const int lane = tid & 63;
    const int wave = tid >> 6;   // 0..7
    const int l15  = lane & 15;
    const int quad = lane >> 4;
    const int wr   = wave >> 2;  // 0..1 (M half, 128 rows)
    const int wc   = wave & 3;   // 0..3 (N quarter, 64 cols)

    // T1: XCD-bijective swizzle (nwg % 8 == 0 for both call sites)
    const int cpx = (int)gridDim.x >> 3;
    const int bid = (int)blockIdx.x;
    const int swz = (bid & 7) * cpx + (bid >> 3);
    const int m0 = (swz / gx) * 256;
    const int n0 = (swz % gx) * 256;

    // staging: thread = (srow = tid>>3 of a 64-row chunk, granule tid&7);
    // source granule pre-swizzled (g ^ (row&7)); LDS dest linear (both-sides rule).
    const int srow = tid >> 3;
    const int sg   = (tid & 7) ^ (srow & 7);
    const s16* Ag = A  + (size_t)(m0 + srow) * K + sg * 8;
    const s16* Bg = Bt + (size_t)(n0 + srow) * K + sg * 8;

#define STG(buf, c, kt) do {                                                        \
    load_lds16(Ag + (size_t)(c) * 64 * K + (size_t)(kt) * 64,                       \
               &As[buf][(c) * 4096 + wave * 512]);                                  \
    load_lds16(Bg + (size_t)(c) * 64 * K + (size_t)(kt) * 64,                       \
               &Bs[buf][(c) * 4096 + wave * 512]); } while (0)

    f32x4 acc[8][4];
#pragma unroll
    for (int i = 0; i < 8; ++i)
#pragma unroll
        for (int j = 0; j < 4; ++j)
            acc[i][j] = (f32x4){0.f, 0.f, 0.f, 0.f};

    const int nk = K >> 6;

    // prologue: stage tile 0 (all 4 chunk-pairs), drain, sync
    STG(0, 0, 0); STG(0, 1, 0); STG(0, 2, 0); STG(0, 3, 0);
    __syncthreads();

    for (int t = 0; t < nk; ++t) {
        const int buf  = t & 1;
        const int nbuf = buf ^ 1;
        const bool pre = (t + 1 < nk);
        bf16x8 bfr[4][2];  // B-frags held across the 4 phases of this K-tile
#pragma unroll
        for (int q = 0; q < 4; ++q) {
            if (q == 0) {
#pragma unroll
                for (int n = 0; n < 4; ++n)
#pragma unroll
                    for (int ks = 0; ks < 2; ++ks) {
                        const int br = wc * 64 + n * 16 + l15;
                        const int gs = ((ks * 4 + quad) ^ (l15 & 7)) * 8;
                        bfr[n][ks] = *(const bf16x8*)(&Bs[buf][br * 64 + gs]);
                    }
            }
            bf16x8 af[2][2];
#pragma unroll
            for (int i = 0; i < 2; ++i)
#pragma unroll
                for (int ks = 0; ks < 2; ++ks) {
                    const int ar = wr * 128 + (q * 2 + i) * 16 + l15;
                    const int gs = ((ks * 4 + quad) ^ (l15 & 7)) * 8;
                    af[i][ks] = *(const bf16x8*)(&As[buf][ar * 64 + gs]);
                }
            // issue next tile's staging early (phases 0-1): 2-3 phases old at drain
            if (q == 0 && pre) { STG(nbuf, 0, t + 1); STG(nbuf, 1, t + 1); }
            if (q == 1 && pre) { STG(nbuf, 2, t + 1); STG(nbuf, 3, t + 1); }
            __builtin_amdgcn_s_barrier();  // phase-align waves
            __builtin_amdgcn_s_setprio(1);
#pragma unroll
            for (int i = 0; i < 2; ++i)
#pragma unroll
                for (int n = 0; n < 4; ++n)
#pragma unroll
                    for (int ks = 0; ks < 2; ++ks)
                        acc[q * 2 + i][n] = __builtin_amdgcn_mfma_f32_16x16x32_bf16(
                            af[i][ks], bfr[n][ks], acc[q * 2 + i][n], 0, 0, 0);
            __builtin_amdgcn_s_setprio(0);
            if (q == 3)
                __syncthreads();  // tile boundary: drain staged loads + sync
            else
                __builtin_amdgcn_s_barrier();
        }
    }
#undef STG

    // epilogue: wave writes its 128x64 block
#pragma unroll
    for (int n = 0; n < 4; ++n) {
        const int col = n0 + wc * 64 + n * 16 + l15;
        const float bv = bias[col];
#pragma unroll
        for (int mf = 0; mf < 8; ++mf) {
            const int rowb = m0 + wr * 128 + mf * 16 + quad * 4;
#pragma unroll
            for (int r = 0; r < 4; ++r) {
                const float v = acc[mf][n][r] + bv;
                if constexpr (OUT_F32)
                    ((float*)Cv)[(size_t)(rowb + r) * N + col] = v;
                else
                    ((s16*)Cv)[(size_t)(rowb + r) * N + col] = f2bf(v);
            }
        }
    }
}

// ---------------------------------------------------------------------------
// Flash attention (causal), fixed-M softmax, S^T formulation. (R10/R13, 80 us proven)
// Flat grid of 1024 blocks = 4/CU resident. bid bits: hi=bid>>8 (CU-sharing round),
// bh=(bid>>2)&63, a=bid&3; qt = hi&1 ? 15-(2a+(hi>>1)) : 2a+(hi>>1).
// -> per-CU qt sets {x, 15-x, x+1, 14-x}: exactly 68 key-tile units per CU.
// ---------------------------------------------------------------------------
__global__ __launch_bounds__(256) void attn_fwd(
    const s16* __restrict__ qkv,
    s16* __restrict__ attn) {
    __shared__ __attribute__((aligned(16))) s16 Ks[64 * 72];
    __shared__ __attribute__((aligned(16))) s16 Vt[64 * 72];
    __shared__ __attribute__((aligned(16))) s16 PT[4][32][88];

    const int tid  = threadIdx.x;
    const int lane = tid & 63;
    const int wave = tid >> 6;
    const int l15  = lane & 15;
    const int quad = lane >> 4;

    // balanced (bh, qt) decomposition (see header comment)
    const int bid = blockIdx.x;
    const int hi  = bid >> 8;
    const int a   = bid & 3;
    const int bh  = (bid >> 2) & 63;
    const int qbase = a * 2 + (hi >> 1);
    const int qt  = (hi & 1) ? 15 - qbase : qbase;

    const size_t rowbase = (size_t)(bh >> 4) * 2048;
    const int hoff = (bh & 15) * 64;
    const int kp  = tid >> 3;  // 0..31: staged key-pair {2kp, 2kp+1}
    const int p_s = tid & 7;   // hd granule
    const int kg  = kp >> 2;   // key granule of this thread's pair

    const float C2 = 0.18033688011112042f;  // 0.125 * log2(e)
    const float M2 = 12.0f;                 // fixed shift (softmax shift-invariant)

    const int wq = qt * 128 + wave * 32;

    // Q fragments: lane holds Q[q = wq + qs*16 + l15][d = ks*32 + quad*8 + j]
    bf16x8 qf[2][2];
#pragma unroll
    for (int qs = 0; qs < 2; ++qs)
#pragma unroll
        for (int ks = 0; ks < 2; ++ks)
            qf[qs][ks] = *(const bf16x8*)(qkv + (rowbase + wq + qs * 16 + l15) * 3072 + hoff + ks * 32 + quad * 8);

    float l_lane[2] = {0.f, 0.f};
    f32x4 o[2][4];  // [qs][hs]; C-layout: q-col = l15, hd-row = hs*16 + quad*4 + r
#pragma unroll
    for (int qs = 0; qs < 2; ++qs)
#pragma unroll
        for (int hs = 0; hs < 4; ++hs)
            o[qs][hs] = (f32x4){0.f, 0.f, 0.f, 0.f};

    const int nkt = qt * 2 + 2;
    // prefetch tile 0 K/V
    bf16x8 kv[2], vv[2];
#pragma unroll
    for (int dk = 0; dk < 2; ++dk) {
        const s16* g = qkv + (rowbase + 2 * kp + dk) * 3072 + hoff + p_s * 8;
        kv[dk] = *(const bf16x8*)(g + 1024);
        vv[dk] = *(const bf16x8*)(g + 2048);
    }

    for (int kt = 0; kt < nkt; ++kt) {
        const int k0 = kt * 64;
        __syncthreads();  // prev iteration's LDS reads done
#pragma unroll
        for (int dk = 0; dk < 2; ++dk)  // K natural layout (R5-proven)
            *(bf16x8*)(Ks + (2 * kp + dk) * 72 + p_s * 8) = kv[dk];
#pragma unroll
        for (int j = 0; j < 8; ++j) {   // V^T swizzled, key-pair b32 (R7-verified)
            const unsigned dw = (unsigned)(unsigned short)vv[0][j] |
                                ((unsigned)(unsigned short)vv[1][j] << 16);
            *(unsigned*)(Vt + (p_s * 8 + j) * 72 + ((kg ^ p_s) << 3) + (2 * kp & 7)) = dw;
        }
        __syncthreads();

        if (kt + 1 < nkt) {  // prefetch next tile under compute
#pragma unroll
            for (int dk = 0; dk < 2; ++dk) {
                const s16* g = qkv + (rowbase + k0 + 64 + 2 * kp + dk) * 3072 + hoff + p_s * 8;
                kv[dk] = *(const bf16x8*)(g + 1024);
                vv[dk] = *(const bf16x8*)(g + 2048);
            }
        }

        if (k0 > wq + 31) continue;  // fully masked for this wave

        // S^T = K Q^T : st[qs][kb], key subtiles kb of 16
        f32x4 st[2][4];
#pragma unroll
        for (int qs = 0; qs < 2; ++qs)
#pragma unroll
            for (int kb = 0; kb < 4; ++kb)
                st[qs][kb] = (f32x4){0.f, 0.f, 0.f, 0.f};
        __builtin_amdgcn_s_setprio(1);
#pragma unroll
        for (int kb = 0; kb < 4; ++kb)
#pragma unroll
            for (int ks = 0; ks < 2; ++ks) {
                const bf16x8 kf = *(const bf16x8*)(Ks + (kb * 16 + l15) * 72 + ks * 32 + quad * 8);
#pragma unroll
                for (int qs = 0; qs < 2; ++qs)
                    st[qs][kb] = __builtin_amdgcn_mfma_f32_16x16x32_bf16(kf, qf[qs][ks], st[qs][kb], 0, 0, 0);
            }
        __builtin_amdgcn_s_setprio(0);

        // softmax (fixed-M) + P^T -> PT (b64, conflict-free)
        const bool edge = (k0 + 63 > wq);
#pragma unroll
        for (int qs = 0; qs < 2; ++qs) {
            const int q = wq + qs * 16 + l15;
#pragma unroll
            for (int kb = 0; kb < 4; ++kb) {
                float p4[4];
#pragma unroll
                for (int r = 0; r < 4; ++r) {
                    float t = fmaf(st[qs][kb][r], C2, -M2);
                    if (edge) {
                        const int key = k0 + kb * 16 + quad * 4 + r;
                        t = (key <= q) ? t : -150.f;  // exp2(-150) == 0
                    }
                    p4[r] = __builtin_amdgcn_exp2f(t);
                    l_lane[qs] += p4[r];
                }
                uint2 dd;
                dd.x = pack_bf16(p4[0], p4[1]);
                dd.y = pack_bf16(p4[2], p4[3]);
                *(uint2*)(&PT[wave][qs * 16 + l15][kb * 16 + quad * 4]) = dd;
            }
        }

        // O^T += V^T P^T
        __builtin_amdgcn_s_setprio(1);
#pragma unroll
        for (int kk = 0; kk < 2; ++kk) {
            bf16x8 pf[2];
#pragma unroll
            for (int qs = 0; qs < 2; ++qs)
                pf[qs] = *(const bf16x8*)(&PT[wave][qs * 16 + l15][kk * 32 + quad * 8]);
#pragma unroll
            for (int hs = 0; hs < 4; ++hs) {
                const bf16x8 vf = *(const bf16x8*)(
                    Vt + (hs * 16 + l15) * 72 + (((kk * 4 + quad) ^ (2 * hs + (l15 >> 3))) << 3));
#pragma unroll
                for (int qs = 0; qs < 2; ++qs)
                    o[qs][hs] = __builtin_amdgcn_mfma_f32_16x16x32_bf16(vf, pf[qs], o[qs][hs], 0, 0, 0);
            }
        }
        __builtin_amdgcn_s_setprio(0);
    }

    // l: sum across the 4 quads (lanes with same l15)
    float rl[2];
#pragma unroll
    for (int qs = 0; qs < 2; ++qs) {
        float l = l_lane[qs];
        l += __shfl_xor(l, 16);
        l += __shfl_xor(l, 32);
        rl[qs] = 1.f / l;
    }

    // epilogue: O^T[hd][q] -> attn[q][hoff+hd]; 4 consecutive hd per reg-quad -> b64
#pragma unroll
    for (int qs = 0; qs < 2; ++qs) {
        const int q = wq + qs * 16 + l15;
#pragma unroll
        for (int hs = 0; hs < 4; ++hs) {
            uint2 dd;
            dd.x = pack_bf16(o[qs][hs][0] * rl[qs], o[qs][hs][1] * rl[qs]);
            dd.y = pack_bf16(o[qs][hs][2] * rl[qs], o[qs][hs][3] * rl[qs]);
            *(uint2*)(attn + (rowbase + q) * 1024 + hoff + hs * 16 + quad * 4) = dd;
        }
    }
}

// ---------------------------------------------------------------------------
extern "C" void kernel_launch(void* const* d_in, const int* in_sizes, int n_in,
                              void* d_out, int out_size, void* d_ws, size_t ws_size,
                              hipStream_t stream) {
    const float* x    = (const float*)d_in[0];  // [8192,1024]
    const float* Wqkv = (const float*)d_in[1];  // [1024,3072]
    const float* bqkv = (const float*)d_in[2];  // [3072]
    const float* Wout = (const float*)d_in[3];  // [1024,1024]
    const float* bout = (const float*)d_in[4];  // [1024]
    float* out = (float*)d_out;                 // [8192,1024] fp32

    s16* ws   = (s16*)d_ws;
    s16* qkv  = ws;                          // [8192,3072] bf16
    s16* xba  = qkv + (size_t)8192 * 3072;   // [8192,1024] bf16: x-cast, later attn output
    s16* wtq  = xba + (size_t)8192 * 1024;   // [3072,1024] bf16
    s16* wto  = wtq + (size_t)3072 * 1024;   // [1024,1024] bf16

    cast_f32_bf16<<<8192, 256, 0, stream>>>(x, xba);
    transpose_cast<<<dim3(3072 / 32, 1024 / 32), dim3(32, 8), 0, stream>>>(Wqkv, wtq, 1024, 3072);
    transpose_cast<<<dim3(1024 / 32, 1024 / 32), dim3(32, 8), 0, stream>>>(Wout, wto, 1024, 1024);
    gemm_bt_bias_256<false><<<384, 512, 0, stream>>>(
        xba, wtq, bqkv, qkv, 8192, 3072, 1024, 12);
    attn_fwd<<<1024, 256, 0, stream>>>(qkv, xba);  // xba dead; reused as attn buf
    gemm_bt_bias_256<true><<<128, 512, 0, stream>>>(
        xba, wto, bout, out, 8192, 1024, 1024, 4);
}